// Round 1
// 314.055 us; speedup vs baseline: 1.0602x; 1.0602x over previous
//
#include <hip/hip_runtime.h>
#include <stdint.h>

typedef unsigned short ushort_t;
typedef __attribute__((ext_vector_type(8))) short short8;
typedef __attribute__((ext_vector_type(4))) float floatx4;

#define B_   8192
#define IN_  1024
#define H_   1024

#define XB_ELEMS   (B_ * IN_)            // 8388608
#define WB_ELEMS   (H_ * IN_)            // 1048576
// ws layout (ushort elements): Xb[8M] | Hb[8M] | Wb[8][1M]  (slots: i,f,g,o x-wts then i,f,g,o h-wts)
#define WS_XB   0
#define WS_HB   XB_ELEMS
#define WS_WB   (2 * XB_ELEMS)

__device__ __forceinline__ ushort_t f2bf(float f) {
    union { float f; uint32_t i; } v; v.f = f;
    uint32_t r = (v.i + 0x7fffu + ((v.i >> 16) & 1u)) >> 16;
    return (ushort_t)r;
}
__device__ __forceinline__ float sigmoid_(float x) {
    return 1.0f / (1.0f + __expf(-x));
}
__device__ __forceinline__ float tanh_(float x) {
    float xc = fminf(fmaxf(x, -20.f), 20.f);
    float e = __expf(2.f * xc);
    return (e - 1.f) / (e + 1.f);
}

// async global->LDS DMA, 16B/lane; dest must be wave-uniform base + lane*16.
__device__ __forceinline__ void gll16(const ushort_t* gsrc, ushort_t* ldst) {
    __builtin_amdgcn_global_load_lds(
        (const __attribute__((address_space(1))) void*)gsrc,
        (__attribute__((address_space(3))) void*)ldst,
        16, 0, 0);
}

// ---- prep: f32 -> bf16 for x, h, 8 weight matrices into ws ----
__global__ __launch_bounds__(256) void cvt_kernel(
    const float* __restrict__ X,   const float* __restrict__ Hin,
    const float* __restrict__ Wix, const float* __restrict__ Wfx,
    const float* __restrict__ Wgx, const float* __restrict__ Wox,
    const float* __restrict__ Wih, const float* __restrict__ Wfh,
    const float* __restrict__ Wgh, const float* __restrict__ Woh,
    ushort_t* __restrict__ ws)
{
    const int c = blockIdx.x * 256 + threadIdx.x;
    const float* src;
    ushort_t* dst;
    int off;
    if (c < 2097152) {
        const int t = c >> 20;                 // 0 = x, 1 = h
        src = t ? Hin : X;
        dst = ws + (t ? WS_HB : WS_XB);
        off = (c & 1048575) * 8;
    } else {
        const int cc = c - 2097152;
        const int s = cc >> 17;                // weight slot 0..7
        const float* w =
            s == 0 ? Wix : s == 1 ? Wfx : s == 2 ? Wgx : s == 3 ? Wox :
            s == 4 ? Wih : s == 5 ? Wfh : s == 6 ? Wgh : Woh;
        src = w;
        dst = ws + WS_WB + s * WB_ELEMS;
        off = (cc & 131071) * 8;
    }
    float4 f0 = *(const float4*)(src + off);
    float4 f1 = *(const float4*)(src + off + 4);
    short8 o;
    o[0] = (short)f2bf(f0.x); o[1] = (short)f2bf(f0.y);
    o[2] = (short)f2bf(f0.z); o[3] = (short)f2bf(f0.w);
    o[4] = (short)f2bf(f1.x); o[5] = (short)f2bf(f1.y);
    o[6] = (short)f2bf(f1.z); o[7] = (short)f2bf(f1.w);
    *(short8*)(dst + off) = o;
}

// ============================================================================
// 256x256 tile, BK=64, 8 waves (2Mx4N), 4-phase-per-K-tile schedule with
// counted vmcnt double buffering (T3+T4) + setprio (T5).
//
// LDS (128 KiB, ushort offsets): slot s in {0,1}:
//   s*32768 + kh*8192          : A half (256 rows x 32 k)   [8192 ush = 16KB]
//   s*32768 + 16384 + kh*8192  : B half (256 vrows x 32 k)
// Within a half: 1024 chunks of 16B; logical (row r, chunk c in 0..3) lives
// at phys idx = r*4 + (c ^ ((r>>1)&3)).  gll dest is linear in idx (DMA
// constraint); the XOR is applied to the *global source* instead.  Fragment
// reads (16 rows x 4 chunks per wave) then hit 8 distinct 16B bank slots per
// 8 consecutive lanes -> conflict-free.
//
// Per K-tile T (slot s = T&1), 4 phases, each {ds_reads; 1 half-tile stage;
// bar; lgkmcnt(0); 16 MFMA; bar}:
//   p0: rf0-3 x k0   + stage A(T+1,k1) -> s^1   (slot freed at T-1 end)
//   p1: rf4-7 x k0   + stage B(T+1,k1) -> s^1
//   p2: rf0-3 x k1   + stage A(T+2,k0) -> s     (A(T,k0) freed after p1)
//   p3: rf4-7 x k1   + stage B(T+2,k0) -> s     (B(T,k0) freed after p0)
//        + vmcnt(4): keeps the last 2 half-tiles (4 loads) in flight; all
//          halves of K-tile T+1 are guaranteed landed.  Never vmcnt(0) in
//          the steady-state loop.
// Virtual col v (0..255): gate=(v>>4)&3, j=j0+(v>>6)*16+(v&15)  -> each
// 16-col fragment is one gate, wave wc holds all 4 gates of 16 j's.
// K order: X k0..1023 (tiles 0-15) then H k0..1023 (16-31) — same
// accumulation order as the previous kernel.
// ============================================================================

#define BAR()  __builtin_amdgcn_s_barrier()
#define LGKM0() do{ asm volatile("s_waitcnt lgkmcnt(0)" ::: "memory"); \
                    __builtin_amdgcn_sched_barrier(0); }while(0)
#define VMC(N) asm volatile("s_waitcnt vmcnt(" #N ")" ::: "memory")

#define STAGE_A(TS, KH, DS) do{ \
    const ushort_t* _s = (((TS) < 16) ? Xb : Hb) + (((TS) & 15) * 64 + (KH) * 32); \
    ushort_t* _d = lds + ((DS) * 32768 + (KH) * 8192); \
    gll16(_s + aoff0,          _d + t * 8); \
    gll16(_s + aoff0 + 131072, _d + 4096 + t * 8); \
  }while(0)

#define STAGE_B(TS, KH, DS) do{ \
    const ushort_t* _s = Wb + ((((TS) < 16) ? 0 : 4 * WB_ELEMS) + (((TS) & 15) * 64 + (KH) * 32)); \
    ushort_t* _d = lds + ((DS) * 32768 + 16384 + (KH) * 8192); \
    gll16(_s + boff0,         _d + t * 8); \
    gll16(_s + boff0 + 32768, _d + 4096 + t * 8); \
  }while(0)

#define RD_A(S, KH, RF) (*(const short8*)(lds + ((S) * 32768 + (KH) * 8192) + a_rd + (RF) * 512))
#define RD_B(S, KH, CT) (*(const short8*)(lds + ((S) * 32768 + 16384 + (KH) * 8192) + b_rd + (CT) * 512))

#define MFMA16(RFB) do{ \
    __builtin_amdgcn_s_setprio(1); \
    _Pragma("unroll") \
    for (int _rf = 0; _rf < 4; ++_rf) \
      _Pragma("unroll") \
      for (int _ct = 0; _ct < 4; ++_ct) \
        acc[(RFB) + _rf][_ct] = __builtin_amdgcn_mfma_f32_16x16x32_bf16( \
            af[_rf], bf[_ct], acc[(RFB) + _rf][_ct], 0, 0, 0); \
    __builtin_amdgcn_s_setprio(0); \
  }while(0)

#define KTILE(T, S, ST01, ST23, VMSTMT) do{ \
    /* p0: rf0-3 x kh0 */ \
    _Pragma("unroll") for (int _r = 0; _r < 4; ++_r) af[_r] = RD_A(S, 0, _r); \
    _Pragma("unroll") for (int _c = 0; _c < 4; ++_c) bf[_c] = RD_B(S, 0, _c); \
    if (ST01) STAGE_A((T) + 1, 1, (S) ^ 1); \
    BAR(); LGKM0(); MFMA16(0); BAR(); \
    /* p1: rf4-7 x kh0 (B frags reused) */ \
    _Pragma("unroll") for (int _r = 0; _r < 4; ++_r) af[_r] = RD_A(S, 0, 4 + _r); \
    if (ST01) STAGE_B((T) + 1, 1, (S) ^ 1); \
    BAR(); LGKM0(); MFMA16(4); BAR(); \
    /* p2: rf0-3 x kh1 */ \
    _Pragma("unroll") for (int _r = 0; _r < 4; ++_r) af[_r] = RD_A(S, 1, _r); \
    _Pragma("unroll") for (int _c = 0; _c < 4; ++_c) bf[_c] = RD_B(S, 1, _c); \
    if (ST23) STAGE_A((T) + 2, 0, S); \
    BAR(); LGKM0(); MFMA16(0); BAR(); \
    /* p3: rf4-7 x kh1 */ \
    _Pragma("unroll") for (int _r = 0; _r < 4; ++_r) af[_r] = RD_A(S, 1, 4 + _r); \
    if (ST23) STAGE_B((T) + 2, 0, S); \
    BAR(); LGKM0(); MFMA16(4); VMSTMT; BAR(); \
  }while(0)

__global__ __launch_bounds__(512, 2) void lstm_cell_kernel(
    const ushort_t* __restrict__ Xb,  const ushort_t* __restrict__ Hb,
    const ushort_t* __restrict__ Wb,  // 8 slots of [H][K] bf16
    const float* __restrict__ Cprev,
    const float* __restrict__ Bi, const float* __restrict__ Bf,
    const float* __restrict__ Bg, const float* __restrict__ Bo,
    float* __restrict__ Out)
{
    __shared__ __align__(16) ushort_t lds[65536];   // 128 KiB

    const int t   = threadIdx.x;                    // 0..511
    const int bm0 = blockIdx.y * 256;
    const int j0  = blockIdx.x * 64;

    // ---- staging precompute: idx = i*512 + t, i in {0,1} ----
    // r = idx>>2 (issue 1: r+128), src chunk c = (idx&3) ^ ((idx>>3)&3)
    // (identical c for both issues since 512>>3 = 64 ≡ 0 mod 4).
    const int r0 = t >> 2;
    const int c0 = (t & 3) ^ ((t >> 3) & 3);
    const int aoff0 = (bm0 + r0) * 1024 + c0 * 8;           // issue1: +131072
    const int g0  = (r0 >> 4) & 3;                          // gate (same both issues)
    const int jv0 = j0 + ((r0 >> 6) << 4) + (r0 & 15);      // issue1: +32 -> +32768
    const int boff0 = g0 * WB_ELEMS + jv0 * 1024 + c0 * 8;

    // ---- fragment read addressing ----
    const int lane = t & 63;
    const int wid  = t >> 6;
    const int wr = wid >> 2, wc = wid & 3;          // 2M x 4N waves
    const int lr = lane & 15, lk = lane >> 4;
    const int xk = lk ^ ((lr >> 1) & 3);            // bank swizzle
    const int a_rd = (wr * 512 + lr * 4 + xk) * 8;  // ushort offset in A half
    const int b_rd = (wc * 256 + lr * 4 + xk) * 8;  // ushort offset in B half

    short8 af[4], bf[4];
    floatx4 acc[8][4] = {};   // [row-frag][gate]

    // ---- prologue: stage halves stream[0..5], allow last 2 in flight ----
    STAGE_A(0, 0, 0); STAGE_B(0, 0, 0);
    STAGE_A(0, 1, 0); STAGE_B(0, 1, 0);
    STAGE_A(1, 0, 1); STAGE_B(1, 0, 1);
    VMC(4);
    BAR();

    // ---- main loop: K-tiles 0..29 fully staged, peel 30/31 ----
    for (int T = 0; T < 30; T += 2) {
        KTILE(T,     0, 1, 1, VMC(4));
        KTILE(T + 1, 1, 1, 1, VMC(4));
    }
    KTILE(30, 0, 1, 0, VMC(0));      // stages only K-tile 31's k1; drain
    KTILE(31, 1, 0, 0, (void)0);

    // ---- epilogue: 4 gates live in acc[rf][0..3], same lane/reg ----
    const int j = j0 + wc * 16 + lr;
    const float bi = Bi[j], bff = Bf[j], bg = Bg[j], bo = Bo[j];

    #pragma unroll
    for (int rf = 0; rf < 8; ++rf) {
        #pragma unroll
        for (int reg = 0; reg < 4; ++reg) {
            const int m = bm0 + wr * 128 + rf * 16 + lk * 4 + reg;
            const float zi = acc[rf][0][reg] + bi;
            const float zf = acc[rf][1][reg] + bff;
            const float zg = acc[rf][2][reg] + bg;
            const float zo = acc[rf][3][reg] + bo;
            const float ig = sigmoid_(zi);
            const float fg = sigmoid_(zf);
            const float gg = tanh_(zg);
            const float og = sigmoid_(zo);
            const float cp = Cprev[(size_t)m * H_ + j];
            const float cn = fg * cp + ig * gg;
            const float hn = og * tanh_(cn);
            Out[(size_t)m * H_ + j] = hn;                             // h_next (f32)
            Out[(size_t)B_ * H_ + (size_t)m * H_ + j] = cn;           // c_next (f32)
        }
    }
}

extern "C" void kernel_launch(void* const* d_in, const int* in_sizes, int n_in,
                              void* d_out, int out_size, void* d_ws, size_t ws_size,
                              hipStream_t stream)
{
    (void)in_sizes; (void)n_in; (void)out_size; (void)ws_size;
    const float* X   = (const float*)d_in[0];
    const float* Hin = (const float*)d_in[1];
    const float* Cp  = (const float*)d_in[2];
    const float* Wfx = (const float*)d_in[3];
    const float* Bf  = (const float*)d_in[4];
    const float* Wfh = (const float*)d_in[5];
    const float* Wix = (const float*)d_in[6];
    const float* Bi  = (const float*)d_in[7];
    const float* Wih = (const float*)d_in[8];
    const float* Wgx = (const float*)d_in[9];
    const float* Bg  = (const float*)d_in[10];
    const float* Wgh = (const float*)d_in[11];
    const float* Wox = (const float*)d_in[12];
    const float* Bo  = (const float*)d_in[13];
    const float* Woh = (const float*)d_in[14];
    float* Out = (float*)d_out;
    ushort_t* ws  = (ushort_t*)d_ws;

    // prep: f32 -> bf16 (x, h, 8 weights) into ws
    cvt_kernel<<<dim3(12288), dim3(256), 0, stream>>>(
        X, Hin, Wix, Wfx, Wgx, Wox, Wih, Wfh, Wgh, Woh, ws);

    dim3 grid(H_ / 64, B_ / 256);   // 16 x 32 = 512 blocks
    lstm_cell_kernel<<<grid, dim3(512), 0, stream>>>(
        ws + WS_XB, ws + WS_HB, ws + WS_WB,
        Cp, Bi, Bf, Bg, Bo, Out);
}